// Round 10
// baseline (167.769 us; speedup 1.0000x reference)
//
#include <hip/hip_runtime.h>

// Token reorderer: stable counting sort by expert id (64 experts).
// Outputs (float32, concatenated): [0,N) sorted scores, [N,2N) permutation,
// [2N,2N+64) per-expert counts.
//
// R17: persistent scatter blocks + cross-tile async prefetch (T14).
//  - Scatter grid = 1024 persistent blocks (4/CU), 2 tiles each. Next tile's
//    idx (2x int4) + scores (8x dword) are issued right after pass-2's
//    barrier -- their HBM latency hides under phase D's stores. One exposed
//    staging latency per BLOCK instead of per TILE; 1024 fewer launches.
//  - Register diet to hold 8 waves/SIMD with prefetch live: running pass-2
//    cursor (no cur[8]), fused bt/wpre accumulation, loop-invariant estart
//    scan hoisted out of the tile loop.
//  - hist/scan identical to R16 (verified).

#define TILE 4096          // elements per tile
#define WAVES 8            // scatter waves per block (512 threads)
#define WCH  512           // elements per scatter wave
#define RND  8             // rounds of 64 per scatter wave
#define TPB  512

__device__ __forceinline__ unsigned long long match_mask(
    unsigned key,
    unsigned long long b0, unsigned long long b1, unsigned long long b2,
    unsigned long long b3, unsigned long long b4, unsigned long long b5,
    unsigned long long am) {
  unsigned long long m = am;
  m &= (key & 1u)  ? b0 : ~b0;
  m &= (key & 2u)  ? b1 : ~b1;
  m &= (key & 4u)  ? b2 : ~b2;
  m &= (key & 8u)  ? b3 : ~b3;
  m &= (key & 16u) ? b4 : ~b4;
  m &= (key & 32u) ? b5 : ~b5;
  return m;
}

// Kernel 1: per-tile expert histogram via ballots (no atomics), 256 threads.
// countsT layout: [tile][64] -> one coalesced 256 B write per block.
__global__ __launch_bounds__(256) void hist_kernel(
    const int* __restrict__ idx, unsigned* __restrict__ countsT,
    int N, int nb) {
  __shared__ unsigned h[4][64];
  const int wave = threadIdx.x >> 6;
  const int lane = threadIdx.x & 63;

  long long base = (long long)blockIdx.x * TILE;
  long long rem = (long long)N - base;
  unsigned cnt = 0;

  if (rem >= TILE) {
    const int4* v = (const int4*)(idx + base);
    unsigned es[16];
    #pragma unroll
    for (int k = 0; k < 4; ++k) {
      int4 x = v[threadIdx.x + k * 256];
      es[k * 4 + 0] = ((unsigned)x.x) & 63u;
      es[k * 4 + 1] = ((unsigned)x.y) & 63u;
      es[k * 4 + 2] = ((unsigned)x.z) & 63u;
      es[k * 4 + 3] = ((unsigned)x.w) & 63u;
    }
    #pragma unroll
    for (int r = 0; r < 16; ++r) {
      unsigned e = es[r];
      unsigned long long b0 = __ballot(e & 1u);
      unsigned long long b1 = __ballot(e & 2u);
      unsigned long long b2 = __ballot(e & 4u);
      unsigned long long b3 = __ballot(e & 8u);
      unsigned long long b4 = __ballot(e & 16u);
      unsigned long long b5 = __ballot(e & 32u);
      cnt += (unsigned)__popcll(
          match_mask((unsigned)lane, b0, b1, b2, b3, b4, b5, ~0ull));
    }
  } else {
    long long wstart = base + (long long)wave * 1024;
    for (int r = 0; r < 16; ++r) {
      long long i = wstart + (long long)r * 64 + lane;
      bool valid = i < (long long)N;
      unsigned long long am = __ballot(valid ? 1 : 0);
      unsigned e = valid ? (((unsigned)idx[i]) & 63u) : 0u;
      unsigned long long b0 = __ballot(e & 1u);
      unsigned long long b1 = __ballot(e & 2u);
      unsigned long long b2 = __ballot(e & 4u);
      unsigned long long b3 = __ballot(e & 8u);
      unsigned long long b4 = __ballot(e & 16u);
      unsigned long long b5 = __ballot(e & 32u);
      cnt += (unsigned)__popcll(
          match_mask((unsigned)lane, b0, b1, b2, b3, b4, b5, am));
    }
  }

  h[wave][lane] = cnt;
  __syncthreads();
  if (threadIdx.x < 64) {
    countsT[(size_t)blockIdx.x * 64 + threadIdx.x] =
        h[0][threadIdx.x] + h[1][threadIdx.x] + h[2][threadIdx.x] + h[3][threadIdx.x];
  }
}

// Kernel 2: per-expert exclusive scan over tiles, chunked through LDS.
// countsT[t*64+e]; strided accesses are L2-resident (512 KB total).
// nb=2048 -> exactly one chunk.
__global__ __launch_bounds__(256) void scan_kernel(
    unsigned* __restrict__ countsT, unsigned* __restrict__ totals,
    float* __restrict__ out_counts, int nb) {
  const int e = blockIdx.x;   // 0..63
  const int t = threadIdx.x;  // 0..255
  const int wave = t >> 6;
  const int lane = t & 63;

  __shared__ unsigned buf[2048];
  __shared__ unsigned wsum[4];

  unsigned carry = 0;
  for (int c = 0; c < nb; c += 2048) {
    int m = nb - c; if (m > 2048) m = 2048;
    for (int j = t; j < 2048; j += 256)
      buf[j] = (j < m) ? countsT[(size_t)(c + j) * 64 + e] : 0u;
    __syncthreads();
    unsigned v[8]; unsigned s = 0;
    #pragma unroll
    for (int k = 0; k < 8; ++k) { v[k] = buf[t * 8 + k]; s += v[k]; }
    unsigned inc = s;
    #pragma unroll
    for (int d = 1; d < 64; d <<= 1) {
      unsigned nv = __shfl_up(inc, d, 64);
      if (lane >= d) inc += nv;
    }
    if (lane == 63) wsum[wave] = inc;
    __syncthreads();
    unsigned woff = 0;
    for (int w = 0; w < wave; ++w) woff += wsum[w];
    unsigned btot = wsum[0] + wsum[1] + wsum[2] + wsum[3];
    unsigned run = carry + woff + (inc - s);
    #pragma unroll
    for (int k = 0; k < 8; ++k) { buf[t * 8 + k] = run; run += v[k]; }
    __syncthreads();
    for (int j = t; j < 2048; j += 256)
      if (j < m) countsT[(size_t)(c + j) * 64 + e] = buf[j];
    carry += btot;
    __syncthreads();
  }
  if (t == 0) {
    totals[e] = carry;
    out_counts[e] = (float)carry;  // output 2
  }
}

// Kernel 3: persistent LDS-staged ballot sort with cross-tile prefetch.
__global__ __launch_bounds__(TPB, 8) void scatter_kernel(
    const int* __restrict__ idx, const float* __restrict__ scores,
    const unsigned* __restrict__ baseT, const unsigned* __restrict__ totals,
    float* __restrict__ out_scores, float* __restrict__ out_idx,
    int N, int nb) {
  // 16-byte aligned: accessed via int4/uint2 casts (ds_*_b128/b64).
  __shared__ __align__(16) uint2 sdat[TILE];                  // 32 KB; first 16 KB alias idx staging
  __shared__ __align__(16) unsigned char tmpb[WAVES][64][RND];// 4 KB leader-publish
  __shared__ unsigned shc[WAVES][64];                         // 2 KB per-wave totals
  __shared__ unsigned gdest[64];                              // dest table

  const int t = threadIdx.x;
  const int wave = t >> 6;
  const int lane = t & 63;
  const unsigned long long lt = (1ull << lane) - 1ull;

  unsigned* idxs = (unsigned*)sdat;  // idx staging aliases sdat (pass-1 only)

  // loop-invariant: global start of expert==lane (exclusive scan of totals)
  unsigned estart;
  {
    unsigned tot = totals[lane];
    unsigned s2 = tot;
    #pragma unroll
    for (int d = 1; d < 64; d <<= 1) {
      unsigned nv = __shfl_up(s2, d, 64);
      if (lane >= d) s2 += nv;
    }
    estart = s2 - tot;
  }

  int tile = blockIdx.x;
  int4 a0, a1;
  float sreg[RND];

  // initial stage load for the first (full) tile
  if (tile < nb && ((long long)(tile + 1) * TILE) <= (long long)N) {
    const long long base = (long long)tile * TILE;
    const int4* gi = (const int4*)(idx + base);
    a0 = gi[t];
    a1 = gi[t + 512];
    const long long start = base + (long long)wave * WCH;
    #pragma unroll
    for (int r = 0; r < RND; ++r) sreg[r] = scores[start + r * 64 + lane];
  }

  while (tile < nb) {
    const long long base = (long long)tile * TILE;
    const long long start = base + (long long)wave * WCH;
    const bool fullt = (base + TILE) <= (long long)N;
    const unsigned gb0 = baseT[(size_t)tile * 64 + lane];  // coalesced
    const int next = tile + (int)gridDim.x;

    unsigned e_pk[2] = {0, 0};
    unsigned r_pk[2] = {0, 0};
    unsigned c_pk[2];

    if (fullt) {
      // ---- Stage from prefetched regs; idx -> LDS via b128 ----
      ((int4*)idxs)[t] = a0;
      ((int4*)idxs)[t + 512] = a1;
      *(uint2*)(&tmpb[wave][lane][0]) = make_uint2(0u, 0u);
      __syncthreads();

      // ---- Pass 1: ballots from LDS; leader publishes per-round count ----
      #pragma unroll
      for (int r = 0; r < RND; ++r) {
        unsigned e = idxs[wave * WCH + r * 64 + lane] & 63u;
        unsigned long long b0 = __ballot(e & 1u);
        unsigned long long b1 = __ballot(e & 2u);
        unsigned long long b2 = __ballot(e & 4u);
        unsigned long long b3 = __ballot(e & 8u);
        unsigned long long b4 = __ballot(e & 16u);
        unsigned long long b5 = __ballot(e & 32u);
        unsigned long long ms = match_mask(e, b0, b1, b2, b3, b4, b5, ~0ull);
        unsigned rank = (unsigned)__popcll(ms & lt);
        unsigned rcnt = (unsigned)__popcll(ms);
        if (rank == 0) tmpb[wave][e][r] = (unsigned char)rcnt;
        const int q = r >> 2, sh = (r & 3) * 8;
        e_pk[q] |= e << sh;
        r_pk[q] |= rank << sh;
      }
      uint2 cw = *(const uint2*)(&tmpb[wave][lane][0]);  // same-wave in-order
      c_pk[0] = cw.x; c_pk[1] = cw.y;
    } else {
      for (int j = t; j < TILE; j += TPB) sdat[j].y = 0xFFFFFFFFu;
      *(uint2*)(&tmpb[wave][lane][0]) = make_uint2(0u, 0u);
      __syncthreads();
      for (int r = 0; r < RND; ++r) {
        long long i = start + (long long)r * 64 + lane;
        bool valid = i < (long long)N;
        unsigned long long am = __ballot(valid ? 1 : 0);
        unsigned e = valid ? (((unsigned)idx[i]) & 63u) : 0u;
        sreg[r] = valid ? scores[i] : 0.0f;
        unsigned long long b0 = __ballot(e & 1u);
        unsigned long long b1 = __ballot(e & 2u);
        unsigned long long b2 = __ballot(e & 4u);
        unsigned long long b3 = __ballot(e & 8u);
        unsigned long long b4 = __ballot(e & 16u);
        unsigned long long b5 = __ballot(e & 32u);
        unsigned long long ms = match_mask(e, b0, b1, b2, b3, b4, b5, am);
        unsigned rank = (unsigned)__popcll(ms & lt);
        unsigned rcnt = (unsigned)__popcll(ms);
        if (valid && rank == 0) tmpb[wave][e][r] = (unsigned char)rcnt;
        const int q = r >> 2, sh = (r & 3) * 8;
        e_pk[q] |= e << sh;
        r_pk[q] |= rank << sh;
      }
      uint2 cw = *(const uint2*)(&tmpb[wave][lane][0]);
      c_pk[0] = cw.x; c_pk[1] = cw.y;
    }

    // wave total for expert==lane = byte-sum of c_pk (SIMD-in-register)
    unsigned wtotal;
    {
      unsigned acc = (c_pk[0] & 0x00FF00FFu) + ((c_pk[0] >> 8) & 0x00FF00FFu)
                   + (c_pk[1] & 0x00FF00FFu) + ((c_pk[1] >> 8) & 0x00FF00FFu);
      wtotal = (acc & 0xFFFFu) + (acc >> 16);
    }

    shc[wave][lane] = wtotal;
    __syncthreads();

    // ---- Block-level geometry for expert == lane ----
    unsigned bt = 0, wpre = 0;
    #pragma unroll
    for (int w = 0; w < WAVES; ++w) {
      unsigned c = shc[w][lane];
      bt += c;
      if (w < wave) wpre += c;
    }

    unsigned s = bt;
    #pragma unroll
    for (int d = 1; d < 64; d <<= 1) {
      unsigned nv = __shfl_up(s, d, 64);
      if (lane >= d) s += nv;
    }
    unsigned bstart = s - bt;
    unsigned wbase = bstart + wpre;   // this wave's start for expert==lane

    // global dest table (wave 0 writes; estart hoisted)
    if (wave == 0) gdest[lane] = estart + gb0 - bstart;  // u32 wraparound ok

    // ---- Pass 2: scatter into block-grouped LDS (running cursor) ----
    unsigned cur_r = wbase;
    if (fullt) {
      #pragma unroll
      for (int r = 0; r < RND; ++r) {
        unsigned i32 = (unsigned)start + r * 64 + lane;
        const int q = r >> 2, sh = (r & 3) * 8;
        unsigned e    = (e_pk[q] >> sh) & 0xffu;
        unsigned rank = (r_pk[q] >> sh) & 0xffu;
        unsigned pos = (unsigned)__shfl((int)cur_r, (int)e, 64) + rank;
        sdat[pos] = make_uint2(__float_as_uint(sreg[r]), (i32 << 6) | e);
        cur_r += (c_pk[q] >> sh) & 0xffu;
      }
    } else {
      for (int r = 0; r < RND; ++r) {
        long long i = start + (long long)r * 64 + lane;
        bool valid = i < (long long)N;
        const int q = r >> 2, sh = (r & 3) * 8;
        unsigned e    = (e_pk[q] >> sh) & 0xffu;
        unsigned rank = (r_pk[q] >> sh) & 0xffu;
        unsigned pos = (unsigned)__shfl((int)cur_r, (int)e, 64) + rank;
        if (valid) {
          sdat[pos] = make_uint2(__float_as_uint(sreg[r]), (((unsigned)i) << 6) | e);
        }
        cur_r += (c_pk[q] >> sh) & 0xffu;
      }
    }
    __syncthreads();

    // ---- Prefetch next tile (a0/a1/sreg now dead) before phase D ----
    if (next < nb && ((long long)(next + 1) * TILE) <= (long long)N) {
      const long long nbase = (long long)next * TILE;
      const int4* gi = (const int4*)(idx + nbase);
      a0 = gi[t];
      a1 = gi[t + 512];
      const long long nstart = nbase + (long long)wave * WCH;
      #pragma unroll
      for (int r = 0; r < RND; ++r) sreg[r] = scores[nstart + r * 64 + lane];
    }

    // ---- Phase D: coalesced write-out ----
    if (fullt) {
      #pragma unroll
      for (int k = 0; k < TILE / TPB; ++k) {
        int j = t + k * TPB;
        uint2 v = sdat[j];
        unsigned e = v.y & 63u;
        unsigned d = gdest[e] + (unsigned)j;
        out_scores[d] = __uint_as_float(v.x);
        out_idx[d] = (float)(v.y >> 6);
      }
    } else {
      for (int j = t; j < TILE; j += TPB) {
        uint2 v = sdat[j];
        if (v.y == 0xFFFFFFFFu) continue;
        unsigned e = v.y & 63u;
        unsigned d = gdest[e] + (unsigned)j;
        out_scores[d] = __uint_as_float(v.x);
        out_idx[d] = (float)(v.y >> 6);
      }
    }
    __syncthreads();  // sdat/gdest safe to overwrite next iteration
    tile = next;
  }
}

extern "C" void kernel_launch(void* const* d_in, const int* in_sizes, int n_in,
                              void* d_out, int out_size, void* d_ws, size_t ws_size,
                              hipStream_t stream) {
  const float* scores = (const float*)d_in[0];
  const int* idx = (const int*)d_in[1];
  int N = in_sizes[0];  // 8388608

  float* out_scores = (float*)d_out;
  float* out_idx = out_scores + N;
  float* out_counts = out_idx + N;

  int nb = (N + TILE - 1) / TILE;                 // 2048
  unsigned* countsT = (unsigned*)d_ws;            // [nb][64], scanned in place
  unsigned* totals = countsT + (size_t)nb * 64;   // [64]

  int sgrid = nb < 1024 ? nb : 1024;              // persistent: 4 blocks/CU, 2 tiles each

  hist_kernel<<<nb, 256, 0, stream>>>(idx, countsT, N, nb);
  scan_kernel<<<64, 256, 0, stream>>>(countsT, totals, out_counts, nb);
  scatter_kernel<<<sgrid, TPB, 0, stream>>>(idx, scores, countsT, totals,
                                            out_scores, out_idx, N, nb);
}

// Round 11
// 138.338 us; speedup vs baseline: 1.2127x; 1.2127x over previous
//
#include <hip/hip_runtime.h>

// Token reorderer: stable counting sort by expert id (64 experts).
// Outputs (float32, concatenated): [0,N) sorted scores, [N,2N) permutation,
// [2N,2N+64) per-expert counts.
//
// R18 = R16 minus intra-block lockstep.
//  - R17's persistent/prefetch schedule REVERTED: stride-1024 tile order
//    destroyed idx L3 reuse (FETCH 33->73 MB) and L2 write-merging of
//    partial lines (WRITE 72.7->140.7 MB). Tile->time adjacency matters.
//  - Wave-local staging: each wave loads+writes its own 512-elem region
//    (2 b128/lane) -> stage barrier DELETED; waves destagger through
//    stage+pass1 and only re-sync at the shc barrier. Compiler reorder
//    fenced with asm memory clobber; HW same-wave DS ordering does the rest.
//  - gdest table -> per-thread register gval (all waves compute the 6-step
//    scan redundantly); phase D uses __shfl(gval, e) (ds_bpermute,
//    conflict-free) instead of random-bank ds_read of gdest[e].
//  - hist/scan verbatim from R16 (verified).

#define TILE 4096          // elements per tile
#define WAVES 8            // scatter waves per block (512 threads)
#define WCH  512           // elements per scatter wave
#define RND  8             // rounds of 64 per scatter wave
#define TPB  512

__device__ __forceinline__ unsigned long long match_mask(
    unsigned key,
    unsigned long long b0, unsigned long long b1, unsigned long long b2,
    unsigned long long b3, unsigned long long b4, unsigned long long b5,
    unsigned long long am) {
  unsigned long long m = am;
  m &= (key & 1u)  ? b0 : ~b0;
  m &= (key & 2u)  ? b1 : ~b1;
  m &= (key & 4u)  ? b2 : ~b2;
  m &= (key & 8u)  ? b3 : ~b3;
  m &= (key & 16u) ? b4 : ~b4;
  m &= (key & 32u) ? b5 : ~b5;
  return m;
}

// Kernel 1: per-tile expert histogram via ballots (no atomics), 256 threads.
// countsT layout: [tile][64] -> one coalesced 256 B write per block.
__global__ __launch_bounds__(256) void hist_kernel(
    const int* __restrict__ idx, unsigned* __restrict__ countsT,
    int N, int nb) {
  __shared__ unsigned h[4][64];
  const int wave = threadIdx.x >> 6;
  const int lane = threadIdx.x & 63;

  long long base = (long long)blockIdx.x * TILE;
  long long rem = (long long)N - base;
  unsigned cnt = 0;

  if (rem >= TILE) {
    const int4* v = (const int4*)(idx + base);
    unsigned es[16];
    #pragma unroll
    for (int k = 0; k < 4; ++k) {
      int4 x = v[threadIdx.x + k * 256];
      es[k * 4 + 0] = ((unsigned)x.x) & 63u;
      es[k * 4 + 1] = ((unsigned)x.y) & 63u;
      es[k * 4 + 2] = ((unsigned)x.z) & 63u;
      es[k * 4 + 3] = ((unsigned)x.w) & 63u;
    }
    #pragma unroll
    for (int r = 0; r < 16; ++r) {
      unsigned e = es[r];
      unsigned long long b0 = __ballot(e & 1u);
      unsigned long long b1 = __ballot(e & 2u);
      unsigned long long b2 = __ballot(e & 4u);
      unsigned long long b3 = __ballot(e & 8u);
      unsigned long long b4 = __ballot(e & 16u);
      unsigned long long b5 = __ballot(e & 32u);
      cnt += (unsigned)__popcll(
          match_mask((unsigned)lane, b0, b1, b2, b3, b4, b5, ~0ull));
    }
  } else {
    long long wstart = base + (long long)wave * 1024;
    for (int r = 0; r < 16; ++r) {
      long long i = wstart + (long long)r * 64 + lane;
      bool valid = i < (long long)N;
      unsigned long long am = __ballot(valid ? 1 : 0);
      unsigned e = valid ? (((unsigned)idx[i]) & 63u) : 0u;
      unsigned long long b0 = __ballot(e & 1u);
      unsigned long long b1 = __ballot(e & 2u);
      unsigned long long b2 = __ballot(e & 4u);
      unsigned long long b3 = __ballot(e & 8u);
      unsigned long long b4 = __ballot(e & 16u);
      unsigned long long b5 = __ballot(e & 32u);
      cnt += (unsigned)__popcll(
          match_mask((unsigned)lane, b0, b1, b2, b3, b4, b5, am));
    }
  }

  h[wave][lane] = cnt;
  __syncthreads();
  if (threadIdx.x < 64) {
    countsT[(size_t)blockIdx.x * 64 + threadIdx.x] =
        h[0][threadIdx.x] + h[1][threadIdx.x] + h[2][threadIdx.x] + h[3][threadIdx.x];
  }
}

// Kernel 2: per-expert exclusive scan over tiles, chunked through LDS.
// countsT[t*64+e]; strided accesses are L2-resident (512 KB total).
// nb=2048 -> exactly one chunk.
__global__ __launch_bounds__(256) void scan_kernel(
    unsigned* __restrict__ countsT, unsigned* __restrict__ totals,
    float* __restrict__ out_counts, int nb) {
  const int e = blockIdx.x;   // 0..63
  const int t = threadIdx.x;  // 0..255
  const int wave = t >> 6;
  const int lane = t & 63;

  __shared__ unsigned buf[2048];
  __shared__ unsigned wsum[4];

  unsigned carry = 0;
  for (int c = 0; c < nb; c += 2048) {
    int m = nb - c; if (m > 2048) m = 2048;
    for (int j = t; j < 2048; j += 256)
      buf[j] = (j < m) ? countsT[(size_t)(c + j) * 64 + e] : 0u;
    __syncthreads();
    unsigned v[8]; unsigned s = 0;
    #pragma unroll
    for (int k = 0; k < 8; ++k) { v[k] = buf[t * 8 + k]; s += v[k]; }
    unsigned inc = s;
    #pragma unroll
    for (int d = 1; d < 64; d <<= 1) {
      unsigned nv = __shfl_up(inc, d, 64);
      if (lane >= d) inc += nv;
    }
    if (lane == 63) wsum[wave] = inc;
    __syncthreads();
    unsigned woff = 0;
    for (int w = 0; w < wave; ++w) woff += wsum[w];
    unsigned btot = wsum[0] + wsum[1] + wsum[2] + wsum[3];
    unsigned run = carry + woff + (inc - s);
    #pragma unroll
    for (int k = 0; k < 8; ++k) { buf[t * 8 + k] = run; run += v[k]; }
    __syncthreads();
    for (int j = t; j < 2048; j += 256)
      if (j < m) countsT[(size_t)(c + j) * 64 + e] = buf[j];
    carry += btot;
    __syncthreads();
  }
  if (t == 0) {
    totals[e] = carry;
    out_counts[e] = (float)carry;  // output 2
  }
}

// Kernel 3: LDS-staged ballot sort; wave-local staging (no stage barrier),
// register dest table via shfl, leader-publish counts, coalesced writes.
__global__ __launch_bounds__(TPB, 8) void scatter_kernel(
    const int* __restrict__ idx, const float* __restrict__ scores,
    const unsigned* __restrict__ baseT, const unsigned* __restrict__ totals,
    float* __restrict__ out_scores, float* __restrict__ out_idx,
    int N, int nb) {
  // 16-byte aligned: accessed via int4/uint2 casts (ds_*_b128/b64).
  __shared__ __align__(16) uint2 sdat[TILE];                  // 32 KB; first 16 KB alias idx staging
  __shared__ __align__(16) unsigned char tmpb[WAVES][64][RND];// 4 KB leader-publish
  __shared__ unsigned shc[WAVES][64];                         // 2 KB per-wave totals

  const int t = threadIdx.x;
  const int wave = t >> 6;
  const int lane = t & 63;
  const unsigned long long lt = (1ull << lane) - 1ull;

  const long long base = (long long)blockIdx.x * TILE;
  const long long start = base + (long long)wave * WCH;
  const bool fullt = (base + TILE) <= (long long)N;

  // hoisted global loads (consumed at table-calc time)
  const unsigned tot = totals[lane];
  const unsigned gb0 = baseT[(size_t)blockIdx.x * 64 + lane];  // coalesced

  unsigned e_pk[2] = {0, 0};
  unsigned r_pk[2] = {0, 0};
  float    sreg[RND];
  unsigned c_pk[2];
  unsigned wtotal = 0;

  unsigned* idxs = (unsigned*)sdat;  // idx staging aliases sdat (pass-1 only)

  if (fullt) {
    // ---- Stage: WAVE-LOCAL idx -> LDS (2 b128/lane into own region) ----
    {
      const int4* gi = (const int4*)(idx + start);   // start 2 KB-aligned
      int4 a0 = gi[lane];
      int4 a1 = gi[lane + 64];
      #pragma unroll
      for (int r = 0; r < RND; ++r) sreg[r] = scores[start + r * 64 + lane];
      ((int4*)idxs)[wave * 128 + lane]      = a0;
      ((int4*)idxs)[wave * 128 + 64 + lane] = a1;
    }
    // zero my tmp row (same-wave DS ordering vs publishes)
    *(uint2*)(&tmpb[wave][lane][0]) = make_uint2(0u, 0u);
    // compiler fence: staging writes above must not reorder past pass-1 reads
    asm volatile("" ::: "memory");
    // NO __syncthreads: pass 1 reads only this wave's region; HW keeps
    // same-wave DS ops in order.

    // ---- Pass 1: ballots from LDS; leader publishes per-round count ----
    #pragma unroll
    for (int r = 0; r < RND; ++r) {
      unsigned e = idxs[wave * WCH + r * 64 + lane] & 63u;
      unsigned long long b0 = __ballot(e & 1u);
      unsigned long long b1 = __ballot(e & 2u);
      unsigned long long b2 = __ballot(e & 4u);
      unsigned long long b3 = __ballot(e & 8u);
      unsigned long long b4 = __ballot(e & 16u);
      unsigned long long b5 = __ballot(e & 32u);
      unsigned long long ms = match_mask(e, b0, b1, b2, b3, b4, b5, ~0ull);
      unsigned rank = (unsigned)__popcll(ms & lt);
      unsigned rcnt = (unsigned)__popcll(ms);
      if (rank == 0) tmpb[wave][e][r] = (unsigned char)rcnt;
      const int q = r >> 2, sh = (r & 3) * 8;
      e_pk[q] |= e << sh;
      r_pk[q] |= rank << sh;
    }
    uint2 cw = *(const uint2*)(&tmpb[wave][lane][0]);  // same-wave in-order
    c_pk[0] = cw.x; c_pk[1] = cw.y;
  } else {
    for (int j = t; j < TILE; j += TPB) sdat[j].y = 0xFFFFFFFFu;
    *(uint2*)(&tmpb[wave][lane][0]) = make_uint2(0u, 0u);
    __syncthreads();
    for (int r = 0; r < RND; ++r) {
      long long i = start + (long long)r * 64 + lane;
      bool valid = i < (long long)N;
      unsigned long long am = __ballot(valid ? 1 : 0);
      unsigned e = valid ? (((unsigned)idx[i]) & 63u) : 0u;
      sreg[r] = valid ? scores[i] : 0.0f;
      unsigned long long b0 = __ballot(e & 1u);
      unsigned long long b1 = __ballot(e & 2u);
      unsigned long long b2 = __ballot(e & 4u);
      unsigned long long b3 = __ballot(e & 8u);
      unsigned long long b4 = __ballot(e & 16u);
      unsigned long long b5 = __ballot(e & 32u);
      unsigned long long ms = match_mask(e, b0, b1, b2, b3, b4, b5, am);
      unsigned rank = (unsigned)__popcll(ms & lt);
      unsigned rcnt = (unsigned)__popcll(ms);
      if (valid && rank == 0) tmpb[wave][e][r] = (unsigned char)rcnt;
      const int q = r >> 2, sh = (r & 3) * 8;
      e_pk[q] |= e << sh;
      r_pk[q] |= rank << sh;
    }
    uint2 cw = *(const uint2*)(&tmpb[wave][lane][0]);
    c_pk[0] = cw.x; c_pk[1] = cw.y;
  }

  // wave total for expert==lane = byte-sum of c_pk (SIMD-in-register)
  {
    unsigned acc = (c_pk[0] & 0x00FF00FFu) + ((c_pk[0] >> 8) & 0x00FF00FFu)
                 + (c_pk[1] & 0x00FF00FFu) + ((c_pk[1] >> 8) & 0x00FF00FFu);
    wtotal = (acc & 0xFFFFu) + (acc >> 16);
  }

  shc[wave][lane] = wtotal;
  __syncthreads();   // barrier A: shc complete; all pass-1 sdat reads done

  // ---- Block-level geometry for expert == lane ----
  unsigned bt = 0, wpre = 0;
  #pragma unroll
  for (int w = 0; w < WAVES; ++w) {
    unsigned c = shc[w][lane];
    bt += c;
    if (w < wave) wpre += c;
  }

  // exclusive scan of block totals over experts -> block-grouped LDS start
  unsigned s = bt;
  #pragma unroll
  for (int d = 1; d < 64; d <<= 1) {
    unsigned nv = __shfl_up(s, d, 64);
    if (lane >= d) s += nv;
  }
  unsigned bstart = s - bt;
  unsigned wbase = bstart + wpre;           // this wave's start for expert==lane

  // global dest base for expert==lane, in REGISTER (all waves redundantly)
  unsigned gval;
  {
    unsigned s2 = tot;
    #pragma unroll
    for (int d = 1; d < 64; d <<= 1) {
      unsigned nv = __shfl_up(s2, d, 64);
      if (lane >= d) s2 += nv;
    }
    unsigned estart = s2 - tot;             // global start of expert==lane
    gval = estart + gb0 - bstart;           // u32 wraparound ok
  }

  // per-round cursors (register prefix)
  unsigned cur[RND];
  {
    unsigned acc = wbase;
    #pragma unroll
    for (int r = 0; r < RND; ++r) {
      cur[r] = acc;
      acc += (c_pk[r >> 2] >> ((r & 3) * 8)) & 0xffu;
    }
  }

  // ---- Pass 2: scatter into block-grouped LDS (reg -> ds_write_b64) ----
  if (fullt) {
    #pragma unroll
    for (int r = 0; r < RND; ++r) {
      unsigned i32 = (unsigned)start + r * 64 + lane;
      const int q = r >> 2, sh = (r & 3) * 8;
      unsigned e    = (e_pk[q] >> sh) & 0xffu;
      unsigned rank = (r_pk[q] >> sh) & 0xffu;
      unsigned pos = (unsigned)__shfl((int)cur[r], (int)e, 64) + rank;
      sdat[pos] = make_uint2(__float_as_uint(sreg[r]), (i32 << 6) | e);
    }
  } else {
    for (int r = 0; r < RND; ++r) {
      long long i = start + (long long)r * 64 + lane;
      bool valid = i < (long long)N;
      const int q = r >> 2, sh = (r & 3) * 8;
      unsigned e    = (e_pk[q] >> sh) & 0xffu;
      unsigned rank = (r_pk[q] >> sh) & 0xffu;
      unsigned pos = (unsigned)__shfl((int)cur[r], (int)e, 64) + rank;
      if (valid) {
        sdat[pos] = make_uint2(__float_as_uint(sreg[r]), (((unsigned)i) << 6) | e);
      }
    }
  }
  __syncthreads();   // barrier B: sdat sorted

  // ---- Phase D: coalesced write-out; dest base via shfl (conflict-free) ----
  if (fullt) {
    #pragma unroll
    for (int k = 0; k < TILE / TPB; ++k) {
      int j = t + k * TPB;
      uint2 v = sdat[j];
      unsigned e = v.y & 63u;
      unsigned d = (unsigned)__shfl((int)gval, (int)e, 64) + (unsigned)j;
      out_scores[d] = __uint_as_float(v.x);
      out_idx[d] = (float)(v.y >> 6);
    }
  } else {
    for (int j = t; j < TILE; j += TPB) {
      uint2 v = sdat[j];
      if (v.y == 0xFFFFFFFFu) continue;
      unsigned e = v.y & 63u;
      unsigned d = (unsigned)__shfl((int)gval, (int)e, 64) + (unsigned)j;
      out_scores[d] = __uint_as_float(v.x);
      out_idx[d] = (float)(v.y >> 6);
    }
  }
}

extern "C" void kernel_launch(void* const* d_in, const int* in_sizes, int n_in,
                              void* d_out, int out_size, void* d_ws, size_t ws_size,
                              hipStream_t stream) {
  const float* scores = (const float*)d_in[0];
  const int* idx = (const int*)d_in[1];
  int N = in_sizes[0];  // 8388608

  float* out_scores = (float*)d_out;
  float* out_idx = out_scores + N;
  float* out_counts = out_idx + N;

  int nb = (N + TILE - 1) / TILE;                 // 2048
  unsigned* countsT = (unsigned*)d_ws;            // [nb][64], scanned in place
  unsigned* totals = countsT + (size_t)nb * 64;   // [64]

  hist_kernel<<<nb, 256, 0, stream>>>(idx, countsT, N, nb);
  scan_kernel<<<64, 256, 0, stream>>>(countsT, totals, out_counts, nb);
  scatter_kernel<<<nb, TPB, 0, stream>>>(idx, scores, countsT, totals,
                                         out_scores, out_idx, N, nb);
}